// Round 1
// baseline (731.162 us; speedup 1.0000x reference)
//
#include <hip/hip_runtime.h>
#include <hip/hip_bf16.h>

#define B_ROWS 32768
#define NTH 1024
#define BQ 128          // rows per block
#define NBLK 256
#define NP 3136         // 64 dims * 49 params
#define NDIM 64

// LDS layout (bytes), total 137216 (<160K):
//   [0,      36864) : h2t bf16 [128][144]  (phase B write, phase C read; survives)
//   [36864,  69632) : h1  bf16 [128][128]  (phase A write, phase B read)
//   [69632, 118784) : W1  bf16 [192][128]  (phase A only)
//   [69632, 102400) : W2  bf16 [128][128]  (phase B, reuses W1 region)
//   [36864, 137216) : raw fp32 [8][3136]   (phase C, reuses h1/W1/W2 regions)

__device__ __forceinline__ float b2f(unsigned int u) {
    union { float f; unsigned int i; } v; v.i = u << 16; return v.f;
}
__device__ __forceinline__ unsigned short f2b(float f) {
    union { float f; unsigned int i; } v; v.f = f;
    unsigned int x = v.i;
    return (unsigned short)((x + 0x7fffu + ((x >> 16) & 1u)) >> 16);
}
__device__ __forceinline__ float splus(float x) {
    // softplus; inputs here are bounded (|x| < ~12) so no overflow path needed
    return __logf(1.0f + __expf(x));
}

__global__ __launch_bounds__(1024, 4) void spline_fused(
    const float* __restrict__ u1, const float* __restrict__ u2,
    const float* __restrict__ cnd, const float* __restrict__ W1,
    const float* __restrict__ b1, const float* __restrict__ W2,
    const float* __restrict__ b2, const float* __restrict__ W3,
    const float* __restrict__ b3, float* __restrict__ out)
{
    __shared__ __align__(16) char smem[137216];
    unsigned short* h2t = (unsigned short*)(smem);           // [128][144] bf16, transposed: [k][row]
    unsigned short* h1b = (unsigned short*)(smem + 36864);   // [128][128] bf16
    unsigned short* w1b = (unsigned short*)(smem + 69632);   // [192][128] bf16
    unsigned short* w2b = (unsigned short*)(smem + 69632);   // [128][128] bf16
    float*          rawt = (float*)(smem + 36864);           // [8][3136] fp32

    const int t = threadIdx.x;
    const int row0 = blockIdx.x * BQ;

    // ---- stage W1 (bf16) ----
    for (int i = t; i < 192 * 128; i += NTH) w1b[i] = f2b(W1[i]);
    __syncthreads();

    // ---- phase A: h1 = relu([u2|cond] @ W1 + b1) ----
    {
        const int j  = t & 127;
        const int rb = t >> 7;            // 0..7
        const float bj = b1[j];
        for (int it = 0; it < 16; ++it) {
            const int r = it * 8 + rb;
            const float* u2r = u2  + (size_t)(row0 + r) * 64;
            const float* cdr = cnd + (size_t)(row0 + r) * 128;
            float acc = bj;
            #pragma unroll 8
            for (int k = 0; k < 64; ++k)
                acc += u2r[k] * b2f(w1b[k * 128 + j]);
            #pragma unroll 8
            for (int k = 0; k < 128; ++k)
                acc += cdr[k] * b2f(w1b[(64 + k) * 128 + j]);
            h1b[r * 128 + j] = f2b(fmaxf(acc, 0.0f));
        }
    }
    __syncthreads();

    // ---- stage W2 (bf16, reuses W1 region) ----
    for (int i = t; i < 128 * 128; i += NTH) w2b[i] = f2b(W2[i]);
    __syncthreads();

    // ---- phase B: h2 = relu(h1 @ W2 + b2), stored transposed bf16 h2t[k][row] ----
    {
        const int j  = t & 127;
        const int rb = t >> 7;
        const float bj = b2[j];
        for (int it = 0; it < 16; ++it) {
            const int r = it * 8 + rb;
            float acc = bj;
            #pragma unroll 8
            for (int k = 0; k < 128; ++k)
                acc += b2f(h1b[r * 128 + k]) * b2f(w2b[k * 128 + j]);
            h2t[j * 144 + r] = f2b(fmaxf(acc, 0.0f));
        }
    }
    __syncthreads();

    const float XS = logf(expm1f(0.625f));   // log(expm1(default_w)), default_w = 10/16
    const float DS = logf(expm1f(1.0f));     // log(e - 1)

    // ---- phase C: 16 chunks of 8 rows: GEMM3 -> raw in LDS -> spline ----
    for (int ci = 0; ci < 16; ++ci) {
        const int lr0 = ci * 8;
        if (t < 784) {                       // 784 * 4 = 3136 cols
            const int c = t * 4;
            float acc[8][4];
            #pragma unroll
            for (int rr = 0; rr < 8; ++rr)
                #pragma unroll
                for (int cc = 0; cc < 4; ++cc) acc[rr][cc] = 0.0f;

            for (int k = 0; k < 128; ++k) {
                const float4 w4 = *(const float4*)(W3 + (size_t)k * NP + c);
                const uint4 hu = *(const uint4*)(h2t + k * 144 + lr0);  // 8 bf16 rows
                float hv[8];
                hv[0] = b2f(hu.x & 0xffffu); hv[1] = b2f(hu.x >> 16);
                hv[2] = b2f(hu.y & 0xffffu); hv[3] = b2f(hu.y >> 16);
                hv[4] = b2f(hu.z & 0xffffu); hv[5] = b2f(hu.z >> 16);
                hv[6] = b2f(hu.w & 0xffffu); hv[7] = b2f(hu.w >> 16);
                #pragma unroll
                for (int rr = 0; rr < 8; ++rr) {
                    acc[rr][0] += hv[rr] * w4.x;
                    acc[rr][1] += hv[rr] * w4.y;
                    acc[rr][2] += hv[rr] * w4.z;
                    acc[rr][3] += hv[rr] * w4.w;
                }
            }
            const float4 bv = *(const float4*)(b3 + c);
            #pragma unroll
            for (int rr = 0; rr < 8; ++rr) {
                float4 o;
                o.x = acc[rr][0] + bv.x; o.y = acc[rr][1] + bv.y;
                o.z = acc[rr][2] + bv.z; o.w = acc[rr][3] + bv.w;
                *(float4*)(rawt + rr * NP + c) = o;
            }
        }
        __syncthreads();

        // ---- spline: 512 tasks = 8 rows x 64 dims; one wave per row ----
        if (t < 512) {
            const int lrow = t >> 6;
            const int dim  = t & 63;
            const int grow = row0 + lr0 + lrow;
            const float* pr = rawt + lrow * NP + dim * 49;
            const float tv = u1[(size_t)grow * 64 + dim];

            const float left   = pr[0] - 5.0f;
            const float bottom = pr[1] - 5.0f;
            float w[16], hh[16];
            float wsum = 0.0f, hsum = 0.0f;
            #pragma unroll
            for (int i = 0; i < 16; ++i) { w[i]  = splus(pr[2 + i]  + XS); wsum += w[i]; }
            #pragma unroll
            for (int i = 0; i < 16; ++i) { hh[i] = splus(pr[18 + i] + XS); hsum += hh[i]; }
            const float scale = hsum / wsum;

            float kx = left;
            int cnt = (kx < tv) ? 1 : 0;
            #pragma unroll
            for (int i = 0; i < 16; ++i) { kx += w[i]; cnt += (kx < tv) ? 1 : 0; }
            const bool indom = (left < tv) && (tv <= kx);
            const int hi = min(max(cnt, 1), 16);
            const int lo = hi - 1;

            float xk = 0.f, xkp = 0.f, yk = 0.f, ykp = 0.f;
            float cx = left, cy = bottom;
            #pragma unroll
            for (int i = 0; i < 16; ++i) {
                const float nx = cx + w[i], ny = cy + hh[i];
                if (i == lo) { xk = cx; xkp = nx; yk = cy; ykp = ny; }
                cx = nx; cy = ny;
            }
            const float dk  = (lo == 0)  ? scale : splus(pr[33 + lo] + DS);
            const float dkp = (hi == 16) ? scale : splus(pr[33 + hi] + DS);

            const float dx = xkp - xk, dy = ykp - yk;
            const float sk = dy / dx;
            float xi = (tv - xk) / dx;
            xi = fminf(fmaxf(xi, 0.0f), 1.0f);
            const float om = 1.0f - xi;
            const float num   = dy * (sk * xi * xi + dk * xi * om);
            const float den   = sk + (dkp + dk - 2.0f * sk) * xi * om;
            const float resin = yk + num / den;
            const float jn    = sk * sk * (dkp * xi * xi + 2.0f * sk * xi * om + dk * om * om);
            const float ljin  = __logf(jn + 1e-10f) - __logf(den * den + 1e-10f);
            const float shift  = bottom - scale * left;
            const float resout = scale * tv + shift;
            const float ljout  = __logf(scale + 1e-10f);

            const float v = indom ? resin : resout;
            float lj = indom ? ljin : ljout;
            out[(size_t)grow * 64 + dim] = v;
            #pragma unroll
            for (int off = 32; off > 0; off >>= 1) lj += __shfl_xor(lj, off, 64);
            if (dim == 0) out[(size_t)B_ROWS * 64 + grow] = lj;
        }
        __syncthreads();
    }
}

extern "C" void kernel_launch(void* const* d_in, const int* in_sizes, int n_in,
                              void* d_out, int out_size, void* d_ws, size_t ws_size,
                              hipStream_t stream) {
    const float* u1 = (const float*)d_in[0];
    const float* u2 = (const float*)d_in[1];
    const float* cd = (const float*)d_in[2];
    const float* W1 = (const float*)d_in[3];
    const float* b1 = (const float*)d_in[4];
    const float* W2 = (const float*)d_in[5];
    const float* b2 = (const float*)d_in[6];
    const float* W3 = (const float*)d_in[7];
    const float* b3 = (const float*)d_in[8];
    spline_fused<<<NBLK, NTH, 0, stream>>>(u1, u2, cd, W1, b1, W2, b2, W3, b3, (float*)d_out);
}

// Round 2
// 335.850 us; speedup vs baseline: 2.1770x; 2.1770x over previous
//
#include <hip/hip_runtime.h>
#include <hip/hip_bf16.h>

// R2: all three GEMMs on bf16 MFMA (16x16x32). prep kernel transposes
// W1/W2/W3 -> bf16 [n][k] in d_ws so B-fragments are contiguous 16B loads.
// Main kernel: 256 blocks x 1024 thr, 128 rows/block, fully fused.
// LDS: h2b[128][136] @0 | h1b[128][136] @34816 | xb[128][200] @69632
//      rawb[64][788] bf16 @34816 (phase C, overlaps h1b/xb) ; total 135680 B.

typedef short bf16x8 __attribute__((ext_vector_type(8)));
typedef float f32x4 __attribute__((ext_vector_type(4)));

#define W3T_OFF 0
#define W1T_OFF 401408
#define W2T_OFF 425984

__device__ __forceinline__ float b2f(unsigned int u) {
    union { float f; unsigned int i; } v; v.i = u << 16; return v.f;
}
__device__ __forceinline__ unsigned short f2b(float f) {
    union { float f; unsigned int i; } v; v.f = f;
    unsigned int x = v.i;
    return (unsigned short)((x + 0x7fffu + ((x >> 16) & 1u)) >> 16);
}
__device__ __forceinline__ float splus(float x) {
    return __logf(1.0f + __expf(x));
}

// ---- prep: fp32 [K][N] -> bf16 [N][K] for W1,W2,W3 (all dims % 64 == 0) ----
__global__ __launch_bounds__(256) void prep_transpose(
    const float* __restrict__ W1, const float* __restrict__ W2,
    const float* __restrict__ W3, unsigned short* __restrict__ ws)
{
    __shared__ float tile[64][65];
    const int bid = blockIdx.x;
    const float* src; unsigned short* dst; int N, Kh, tk, tn;
    if (bid < 98)       { src = W3; dst = ws + W3T_OFF; N = 3136; Kh = 64; tk = bid & 1; tn = bid >> 1; }
    else if (bid < 104) { int b = bid - 98;  src = W1; dst = ws + W1T_OFF; N = 128; Kh = 96; tk = b % 3; tn = b / 3; }
    else                { int b = bid - 104; src = W2; dst = ws + W2T_OFF; N = 128; Kh = 64; tk = b & 1; tn = b >> 1; }
    const int t = threadIdx.x;
    const int nl = t & 63, kq = t >> 6;
    #pragma unroll
    for (int i = 0; i < 16; ++i) {
        int kl = i * 4 + kq;
        tile[kl][nl] = src[(size_t)(tk * 64 + kl) * N + tn * 64 + nl];
    }
    __syncthreads();
    unsigned int* d32 = (unsigned int*)dst;
    const int kp = t & 31, nq = t >> 5;
    #pragma unroll
    for (int i = 0; i < 8; ++i) {
        int n = i * 8 + nq;
        unsigned int lo = f2b(tile[2 * kp][n]);
        unsigned int hi = f2b(tile[2 * kp + 1][n]);
        d32[(size_t)(tn * 64 + n) * Kh + tk * 32 + kp] = lo | (hi << 16);
    }
}

__global__ __launch_bounds__(1024) void spline_main(
    const float* __restrict__ u1, const float* __restrict__ u2,
    const float* __restrict__ cnd, const float* __restrict__ b1,
    const float* __restrict__ b2, const float* __restrict__ b3,
    const unsigned short* __restrict__ ws, float* __restrict__ out)
{
    __shared__ __align__(16) char smem[135680];
    unsigned short* h2b  = (unsigned short*)smem;            // [128][136]
    unsigned short* h1b  = (unsigned short*)(smem + 34816);  // [128][136]
    unsigned short* xb   = (unsigned short*)(smem + 69632);  // [128][200]
    unsigned short* rawb = (unsigned short*)(smem + 34816);  // [64][788]
    const unsigned short* W3T = ws + W3T_OFF;  // [3136][128]
    const unsigned short* W1T = ws + W1T_OFF;  // [128][192]
    const unsigned short* W2T = ws + W2T_OFF;  // [128][128]

    const int t = threadIdx.x;
    const int row0 = blockIdx.x * 128;
    const int w = t >> 6, lane = t & 63;
    const int l15 = lane & 15, lg = lane >> 4;

    // ---- stage x = [u2 | cond] as bf16 into xb ----
    {
        const float2* u2v = (const float2*)(u2 + (size_t)row0 * 64);
        #pragma unroll
        for (int p = 0; p < 4; ++p) {
            int idx = t + p * 1024;                 // 4096 float2
            int r = idx >> 5, c2 = idx & 31;
            float2 v = u2v[idx];
            *(unsigned int*)((char*)xb + r * 400 + c2 * 4) =
                (unsigned int)f2b(v.x) | ((unsigned int)f2b(v.y) << 16);
        }
        const float2* cdv = (const float2*)(cnd + (size_t)row0 * 128);
        #pragma unroll
        for (int p = 0; p < 8; ++p) {
            int idx = t + p * 1024;                 // 8192 float2
            int r = idx >> 6, c2 = idx & 63;
            float2 v = cdv[idx];
            *(unsigned int*)((char*)xb + r * 400 + 128 + c2 * 4) =
                (unsigned int)f2b(v.x) | ((unsigned int)f2b(v.y) << 16);
        }
    }
    __syncthreads();

    // ---- phase A: h1 = relu(x @ W1 + b1), M=128 N=128 K=192 ----
    {
        const int mt = w >> 1;
        bf16x8 af[6];
        #pragma unroll
        for (int kg = 0; kg < 6; ++kg)
            af[kg] = *(const bf16x8*)((char*)xb + (mt * 16 + l15) * 400 + kg * 64 + lg * 16);
        #pragma unroll
        for (int ni = 0; ni < 4; ++ni) {
            int nt = (w & 1) + ni * 2;
            int j = nt * 16 + l15;
            f32x4 acc = {0.f, 0.f, 0.f, 0.f};
            #pragma unroll
            for (int kg = 0; kg < 6; ++kg) {
                bf16x8 bf = *(const bf16x8*)(W1T + (size_t)j * 192 + kg * 32 + lg * 8);
                acc = __builtin_amdgcn_mfma_f32_16x16x32_bf16(af[kg], bf, acc, 0, 0, 0);
            }
            float bj = b1[j];
            #pragma unroll
            for (int r = 0; r < 4; ++r) {
                int ro = mt * 16 + lg * 4 + r;
                h1b[ro * 136 + j] = f2b(fmaxf(acc[r] + bj, 0.f));
            }
        }
    }
    __syncthreads();

    // ---- phase B: h2 = relu(h1 @ W2 + b2), M=128 N=128 K=128 ----
    {
        const int mt = w >> 1;
        bf16x8 af[4];
        #pragma unroll
        for (int kg = 0; kg < 4; ++kg)
            af[kg] = *(const bf16x8*)((char*)h1b + (mt * 16 + l15) * 272 + kg * 64 + lg * 16);
        #pragma unroll
        for (int ni = 0; ni < 4; ++ni) {
            int nt = (w & 1) + ni * 2;
            int j = nt * 16 + l15;
            f32x4 acc = {0.f, 0.f, 0.f, 0.f};
            #pragma unroll
            for (int kg = 0; kg < 4; ++kg) {
                bf16x8 bf = *(const bf16x8*)(W2T + (size_t)j * 128 + kg * 32 + lg * 8);
                acc = __builtin_amdgcn_mfma_f32_16x16x32_bf16(af[kg], bf, acc, 0, 0, 0);
            }
            float bj = b2[j];
            #pragma unroll
            for (int r = 0; r < 4; ++r) {
                int ro = mt * 16 + lg * 4 + r;
                h2b[ro * 136 + j] = f2b(fmaxf(acc[r] + bj, 0.f));
            }
        }
    }
    __syncthreads();

    const float XS = logf(expm1f(0.625f));
    const float DS = logf(expm1f(1.0f));

    // ---- phase C: 2 row-groups x 4 dim-chunks; GEMM3 tile -> rawb -> spline ----
    const int mt3 = w & 3, ng = w >> 2;
    for (int rg = 0; rg < 2; ++rg) {
        bf16x8 a3[4];
        #pragma unroll
        for (int kg = 0; kg < 4; ++kg)
            a3[kg] = *(const bf16x8*)((char*)h2b + (rg * 64 + mt3 * 16 + l15) * 272 + kg * 64 + lg * 16);
        float lja = 0.f;

        for (int dc = 0; dc < 4; ++dc) {
            // GEMM3 chunk: M=64 (4 tiles), N=784 (49 tiles), K=128
            bf16x8 bf0[4];
            {
                int colg = dc * 784 + ng * 16 + l15;
                #pragma unroll
                for (int kg = 0; kg < 4; ++kg)
                    bf0[kg] = *(const bf16x8*)(W3T + (size_t)colg * 128 + kg * 32 + lg * 8);
            }
            for (int nt = ng; nt < 49; nt += 4) {
                int ntn = nt + 4;
                bf16x8 bf1[4];
                if (ntn < 49) {
                    int colg2 = dc * 784 + ntn * 16 + l15;
                    #pragma unroll
                    for (int kg = 0; kg < 4; ++kg)
                        bf1[kg] = *(const bf16x8*)(W3T + (size_t)colg2 * 128 + kg * 32 + lg * 8);
                }
                int colg = dc * 784 + nt * 16 + l15;
                float bj = b3[colg];
                f32x4 acc0 = {0.f, 0.f, 0.f, 0.f}, acc1 = {0.f, 0.f, 0.f, 0.f};
                acc0 = __builtin_amdgcn_mfma_f32_16x16x32_bf16(a3[0], bf0[0], acc0, 0, 0, 0);
                acc1 = __builtin_amdgcn_mfma_f32_16x16x32_bf16(a3[1], bf0[1], acc1, 0, 0, 0);
                acc0 = __builtin_amdgcn_mfma_f32_16x16x32_bf16(a3[2], bf0[2], acc0, 0, 0, 0);
                acc1 = __builtin_amdgcn_mfma_f32_16x16x32_bf16(a3[3], bf0[3], acc1, 0, 0, 0);
                #pragma unroll
                for (int r = 0; r < 4; ++r) {
                    int lr = mt3 * 16 + lg * 4 + r;
                    rawb[lr * 788 + nt * 16 + l15] = f2b(acc0[r] + acc1[r] + bj);
                }
                #pragma unroll
                for (int kg = 0; kg < 4; ++kg) bf0[kg] = bf1[kg];
            }
            __syncthreads();

            // spline for 64 rows x 16 dims (1 task/thread)
            {
                const int lrow = t >> 4, dsl = t & 15;
                const int dim = dc * 16 + dsl;
                const int grow = row0 + rg * 64 + lrow;
                const unsigned short* pr = rawb + lrow * 788 + dsl * 49;
                const float tv = u1[(size_t)grow * 64 + dim];
                const float left   = b2f(pr[0]) - 5.0f;
                const float bottom = b2f(pr[1]) - 5.0f;
                float wv[16], hv[16];
                float wsum = 0.f, hsum = 0.f;
                #pragma unroll
                for (int i = 0; i < 16; ++i) { wv[i] = splus(b2f(pr[2 + i])  + XS); wsum += wv[i]; }
                #pragma unroll
                for (int i = 0; i < 16; ++i) { hv[i] = splus(b2f(pr[18 + i]) + XS); hsum += hv[i]; }
                const float scale = hsum / wsum;
                float kx = left; int cnt = (kx < tv) ? 1 : 0;
                #pragma unroll
                for (int i = 0; i < 16; ++i) { kx += wv[i]; cnt += (kx < tv) ? 1 : 0; }
                const bool indom = (left < tv) && (tv <= kx);
                const int hi = min(max(cnt, 1), 16);
                const int lo = hi - 1;
                float xk = 0.f, xkp = 0.f, yk = 0.f, ykp = 0.f;
                float cx = left, cy = bottom;
                #pragma unroll
                for (int i = 0; i < 16; ++i) {
                    float nx = cx + wv[i], ny = cy + hv[i];
                    if (i == lo) { xk = cx; xkp = nx; yk = cy; ykp = ny; }
                    cx = nx; cy = ny;
                }
                const float dk  = (lo == 0)  ? scale : splus(b2f(pr[33 + lo]) + DS);
                const float dkp = (hi == 16) ? scale : splus(b2f(pr[33 + hi]) + DS);
                const float dxk = xkp - xk, dyk = ykp - yk;
                const float sk = dyk / dxk;
                float xi = (tv - xk) / dxk;
                xi = fminf(fmaxf(xi, 0.f), 1.f);
                const float om = 1.f - xi;
                const float num = dyk * (sk * xi * xi + dk * xi * om);
                const float den = sk + (dkp + dk - 2.f * sk) * xi * om;
                const float resin = yk + num / den;
                const float jn = sk * sk * (dkp * xi * xi + 2.f * sk * xi * om + dk * om * om);
                const float ljin = __logf(jn + 1e-10f) - __logf(den * den + 1e-10f);
                const float resout = scale * tv + (bottom - scale * left);
                const float ljout = __logf(scale + 1e-10f);
                out[(size_t)grow * 64 + dim] = indom ? resin : resout;
                lja += indom ? ljin : ljout;
            }
            __syncthreads();
        }
        // reduce log-det over the 16 dim-slot lanes of each row
        float lj = lja;
        lj += __shfl_xor(lj, 1, 64);
        lj += __shfl_xor(lj, 2, 64);
        lj += __shfl_xor(lj, 4, 64);
        lj += __shfl_xor(lj, 8, 64);
        if ((t & 15) == 0) {
            int grow = row0 + rg * 64 + (t >> 4);
            out[(size_t)32768 * 64 + grow] = lj;
        }
    }
}

extern "C" void kernel_launch(void* const* d_in, const int* in_sizes, int n_in,
                              void* d_out, int out_size, void* d_ws, size_t ws_size,
                              hipStream_t stream) {
    const float* u1 = (const float*)d_in[0];
    const float* u2 = (const float*)d_in[1];
    const float* cd = (const float*)d_in[2];
    const float* W1 = (const float*)d_in[3];
    const float* b1 = (const float*)d_in[4];
    const float* W2 = (const float*)d_in[5];
    const float* b2 = (const float*)d_in[6];
    const float* W3 = (const float*)d_in[7];
    const float* b3 = (const float*)d_in[8];
    unsigned short* ws = (unsigned short*)d_ws;
    prep_transpose<<<108, 256, 0, stream>>>(W1, W2, W3, ws);
    spline_main<<<256, 1024, 0, stream>>>(u1, u2, cd, b1, b2, b3, ws, (float*)d_out);
}

// Round 5
// 327.209 us; speedup vs baseline: 2.2345x; 1.0264x over previous
//
#include <hip/hip_runtime.h>
#include <hip/hip_bf16.h>

// R5: R3 structure (512 blocks x 512 thr, 64 rows/block, 74KB LDS -> 2 blocks/CU)
// + fix: spline param union loads 7 uint4 (56 shorts), not 4 (which left
// s[32..48] = heights[14..15] + all der params uninitialized -> R4 fail).

typedef short bf16x8 __attribute__((ext_vector_type(8)));
typedef float f32x4 __attribute__((ext_vector_type(4)));

// ws byte offsets
#define W3T_B 0           // [3584][128] bf16 = 917504 B
#define W1T_B 917504      // [128][192] bf16 = 49152 B
#define W2T_B 966656      // [128][128] bf16 = 32768 B
#define B3P_B 999424      // [3584] f32  = 14336 B

__device__ __forceinline__ float b2f(unsigned int u) {
    union { float f; unsigned int i; } v; v.i = u << 16; return v.f;
}
__device__ __forceinline__ unsigned short f2b(float f) {
    union { float f; unsigned int i; } v; v.f = f;
    unsigned int x = v.i;
    return (unsigned short)((x + 0x7fffu + ((x >> 16) & 1u)) >> 16);
}
__device__ __forceinline__ float splus(float x) {
    return __logf(1.0f + __expf(x));
}

// ---- prep: W1/W2 transpose, W3 permute+pad+transpose, b3 pad ----
__global__ __launch_bounds__(256) void prep(
    const float* __restrict__ W1, const float* __restrict__ W2,
    const float* __restrict__ W3, const float* __restrict__ b3,
    char* __restrict__ ws)
{
    __shared__ __align__(16) float tbuf[4224];
    const int b = blockIdx.x, t = threadIdx.x;
    if (b < 112) {
        // W3: dst cols [b*32, b*32+32) of [3584][128]
        unsigned short* W3T = (unsigned short*)(ws + W3T_B);
        const int c0 = b * 32;
        #pragma unroll
        for (int i = 0; i < 16; ++i) {
            int idx = i * 256 + t;
            int c = idx & 31, k = idx >> 5;
            unsigned int cg = (unsigned int)(c0 + c);
            unsigned int dim = cg / 56u, p = cg % 56u;
            float v = (p < 49u) ? W3[(size_t)k * 3136 + dim * 49 + p] : 0.0f;
            tbuf[c * 132 + k] = v;
        }
        __syncthreads();
        const int c = t >> 3, kg = (t & 7) * 16;
        unsigned int d[8];
        #pragma unroll
        for (int i = 0; i < 8; ++i) {
            unsigned int lo = f2b(tbuf[c * 132 + kg + 2 * i]);
            unsigned int hi = f2b(tbuf[c * 132 + kg + 2 * i + 1]);
            d[i] = lo | (hi << 16);
        }
        uint4* dst = (uint4*)(W3T + (size_t)(c0 + c) * 128 + kg);
        dst[0] = make_uint4(d[0], d[1], d[2], d[3]);
        dst[1] = make_uint4(d[4], d[5], d[6], d[7]);
    } else if (b < 122) {
        const float* src; unsigned short* dst; int Kdw, tk, tn;
        if (b < 118) { int lb = b - 112; src = W1; dst = (unsigned short*)(ws + W1T_B); Kdw = 96; tk = lb % 3; tn = lb / 3; }
        else         { int lb = b - 118; src = W2; dst = (unsigned short*)(ws + W2T_B); Kdw = 64; tk = lb & 1; tn = lb >> 1; }
        const int nl = t & 63, kq = t >> 6;
        #pragma unroll
        for (int i = 0; i < 16; ++i) {
            int kl = i * 4 + kq;
            tbuf[kl * 65 + nl] = src[(size_t)(tk * 64 + kl) * 128 + tn * 64 + nl];
        }
        __syncthreads();
        unsigned int* d32 = (unsigned int*)dst;
        const int kp = t & 31, nq = t >> 5;
        #pragma unroll
        for (int i = 0; i < 8; ++i) {
            int n = i * 8 + nq;
            unsigned int lo = f2b(tbuf[(2 * kp) * 65 + n]);
            unsigned int hi = f2b(tbuf[(2 * kp + 1) * 65 + n]);
            d32[(size_t)(tn * 64 + n) * Kdw + tk * 32 + kp] = lo | (hi << 16);
        }
    } else {
        int c = (b - 122) * 256 + t;
        unsigned int dim = (unsigned int)c / 56u, p = (unsigned int)c % 56u;
        float* b3p = (float*)(ws + B3P_B);
        b3p[c] = (p < 49u) ? b3[dim * 49 + p] : 0.0f;
    }
}

// LDS: h2b[64][136] @0 | xb[64][200] @17408 | h1b[64][136] @43008
//      rawb[64][456] @17408 (phase C, overlaps xb/h1b). total 75776 B.
__global__ __launch_bounds__(512, 4) void spline_main(
    const float* __restrict__ u1, const float* __restrict__ u2,
    const float* __restrict__ cnd, const float* __restrict__ b1,
    const float* __restrict__ b2, const char* __restrict__ ws,
    float* __restrict__ out)
{
    __shared__ __align__(16) char smem[75776];
    unsigned short* h2b  = (unsigned short*)smem;            // [64][136]
    unsigned short* xb   = (unsigned short*)(smem + 17408);  // [64][200]
    unsigned short* h1b  = (unsigned short*)(smem + 43008);  // [64][136]
    unsigned short* rawb = (unsigned short*)(smem + 17408);  // [64][456]
    const unsigned short* W3T = (const unsigned short*)(ws + W3T_B);
    const unsigned short* W1T = (const unsigned short*)(ws + W1T_B);
    const unsigned short* W2T = (const unsigned short*)(ws + W2T_B);
    const float* b3p = (const float*)(ws + B3P_B);

    const int t = threadIdx.x;
    const int row0 = blockIdx.x * 64;
    const int w = t >> 6, lane = t & 63;
    const int l15 = lane & 15, lg = lane >> 4;

    // ---- stage x = [u2 | cond] bf16 ----
    {
        const float2* u2v = (const float2*)(u2 + (size_t)row0 * 64);
        #pragma unroll
        for (int p = 0; p < 4; ++p) {
            int idx = t + p * 512;
            int r = idx >> 5, c2 = idx & 31;
            float2 v = u2v[idx];
            *(unsigned int*)((char*)xb + r * 400 + c2 * 4) =
                (unsigned int)f2b(v.x) | ((unsigned int)f2b(v.y) << 16);
        }
        const float2* cdv = (const float2*)(cnd + (size_t)row0 * 128);
        #pragma unroll
        for (int p = 0; p < 8; ++p) {
            int idx = t + p * 512;
            int r = idx >> 6, c2 = idx & 63;
            float2 v = cdv[idx];
            *(unsigned int*)((char*)xb + r * 400 + 128 + c2 * 4) =
                (unsigned int)f2b(v.x) | ((unsigned int)f2b(v.y) << 16);
        }
    }
    __syncthreads();

    // ---- phase A: h1 = relu(x @ W1 + b1), M=64 N=128 K=192 ----
    {
        const int mt = w >> 1;
        bf16x8 af[6];
        #pragma unroll
        for (int kg = 0; kg < 6; ++kg)
            af[kg] = *(const bf16x8*)((char*)xb + (mt * 16 + l15) * 400 + kg * 64 + lg * 16);
        #pragma unroll
        for (int ni = 0; ni < 4; ++ni) {
            int nt = (w & 1) + ni * 2;
            int j = nt * 16 + l15;
            f32x4 acc = {0.f, 0.f, 0.f, 0.f};
            #pragma unroll
            for (int kg = 0; kg < 6; ++kg) {
                bf16x8 bf = *(const bf16x8*)(W1T + (size_t)j * 192 + kg * 32 + lg * 8);
                acc = __builtin_amdgcn_mfma_f32_16x16x32_bf16(af[kg], bf, acc, 0, 0, 0);
            }
            float bj = b1[j];
            #pragma unroll
            for (int r = 0; r < 4; ++r)
                h1b[(mt * 16 + lg * 4 + r) * 136 + j] = f2b(fmaxf(acc[r] + bj, 0.f));
        }
    }
    __syncthreads();

    // ---- phase B: h2 = relu(h1 @ W2 + b2), M=64 N=128 K=128 ----
    {
        const int mt = w >> 1;
        bf16x8 af[4];
        #pragma unroll
        for (int kg = 0; kg < 4; ++kg)
            af[kg] = *(const bf16x8*)((char*)h1b + (mt * 16 + l15) * 272 + kg * 64 + lg * 16);
        #pragma unroll
        for (int ni = 0; ni < 4; ++ni) {
            int nt = (w & 1) + ni * 2;
            int j = nt * 16 + l15;
            f32x4 acc = {0.f, 0.f, 0.f, 0.f};
            #pragma unroll
            for (int kg = 0; kg < 4; ++kg) {
                bf16x8 bf = *(const bf16x8*)(W2T + (size_t)j * 128 + kg * 32 + lg * 8);
                acc = __builtin_amdgcn_mfma_f32_16x16x32_bf16(af[kg], bf, acc, 0, 0, 0);
            }
            float bj = b2[j];
            #pragma unroll
            for (int r = 0; r < 4; ++r)
                h2b[(mt * 16 + lg * 4 + r) * 136 + j] = f2b(fmaxf(acc[r] + bj, 0.f));
        }
    }
    __syncthreads();

    const float XS = logf(expm1f(0.625f));
    const float DS = logf(expm1f(1.0f));

    // ---- phase C: 8 chunks of 8 dims; GEMM3 tile (N=448) -> rawb -> spline ----
    const int mt3 = w & 3, ng = w >> 2;
    bf16x8 a3[4];
    #pragma unroll
    for (int kg = 0; kg < 4; ++kg)
        a3[kg] = *(const bf16x8*)((char*)h2b + (mt3 * 16 + l15) * 272 + kg * 64 + lg * 16);
    const int lrow = t >> 3, dsl = t & 7;
    float lja = 0.f;

    for (int dc = 0; dc < 8; ++dc) {
        const float tv = u1[(size_t)(row0 + lrow) * 64 + dc * 8 + dsl];

        // GEMM chunk: M=64 (4 m-tiles), N=448 (28 n-tiles), K=128
        {
            bf16x8 bf0[4];
            {
                int colg = dc * 448 + ng * 16 + l15;
                #pragma unroll
                for (int kg = 0; kg < 4; ++kg)
                    bf0[kg] = *(const bf16x8*)(W3T + (size_t)colg * 128 + kg * 32 + lg * 8);
            }
            for (int nt = ng; nt < 28; nt += 2) {
                int colg = dc * 448 + nt * 16 + l15;
                bf16x8 bf1[4];
                if (nt + 2 < 28) {
                    #pragma unroll
                    for (int kg = 0; kg < 4; ++kg)
                        bf1[kg] = *(const bf16x8*)(W3T + (size_t)(colg + 32) * 128 + kg * 32 + lg * 8);
                }
                float bj = b3p[colg];
                f32x4 acc0 = {0.f, 0.f, 0.f, 0.f}, acc1 = {0.f, 0.f, 0.f, 0.f};
                acc0 = __builtin_amdgcn_mfma_f32_16x16x32_bf16(a3[0], bf0[0], acc0, 0, 0, 0);
                acc1 = __builtin_amdgcn_mfma_f32_16x16x32_bf16(a3[1], bf0[1], acc1, 0, 0, 0);
                acc0 = __builtin_amdgcn_mfma_f32_16x16x32_bf16(a3[2], bf0[2], acc0, 0, 0, 0);
                acc1 = __builtin_amdgcn_mfma_f32_16x16x32_bf16(a3[3], bf0[3], acc1, 0, 0, 0);
                #pragma unroll
                for (int r = 0; r < 4; ++r)
                    rawb[(mt3 * 16 + lg * 4 + r) * 456 + nt * 16 + l15] =
                        f2b(acc0[r] + acc1[r] + bj);
                #pragma unroll
                for (int kg = 0; kg < 4; ++kg) bf0[kg] = bf1[kg];
            }
        }
        __syncthreads();

        // spline: 512 tasks = 64 rows x 8 dims
        {
            union { uint4 q[7]; unsigned short s[56]; } P;   // FULL 56-short row (R4 bug: was q[4])
            const uint4* pq = (const uint4*)(rawb + lrow * 456 + dsl * 56);
            #pragma unroll
            for (int i = 0; i < 7; ++i) P.q[i] = pq[i];

            const float left   = b2f(P.s[0]) - 5.0f;
            const float bottom = b2f(P.s[1]) - 5.0f;
            float wv[16], hv[16];
            float wsum = 0.f, hsum = 0.f;
            #pragma unroll
            for (int i = 0; i < 16; ++i) { wv[i] = splus(b2f(P.s[2 + i])  + XS); wsum += wv[i]; }
            #pragma unroll
            for (int i = 0; i < 16; ++i) { hv[i] = splus(b2f(P.s[18 + i]) + XS); hsum += hv[i]; }
            const float scale = hsum / wsum;
            float kx = left; int cnt = (kx < tv) ? 1 : 0;
            #pragma unroll
            for (int i = 0; i < 16; ++i) { kx += wv[i]; cnt += (kx < tv) ? 1 : 0; }
            const bool indom = (left < tv) && (tv <= kx);
            const int hi = min(max(cnt, 1), 16);
            const int lo = hi - 1;
            float xk = 0.f, xkp = 0.f, yk = 0.f, ykp = 0.f;
            float cx = left, cy = bottom;
            #pragma unroll
            for (int i = 0; i < 16; ++i) {
                float nx = cx + wv[i], ny = cy + hv[i];
                if (i == lo) { xk = cx; xkp = nx; yk = cy; ykp = ny; }
                cx = nx; cy = ny;
            }
            // runtime-indexed der params from LDS (not P regs) to avoid scratch
            const unsigned short* prd = rawb + lrow * 456 + dsl * 56;
            const float dk  = (lo == 0)  ? scale : splus(b2f(prd[33 + lo]) + DS);
            const float dkp = (hi == 16) ? scale : splus(b2f(prd[33 + hi]) + DS);
            const float dxk = xkp - xk, dyk = ykp - yk;
            const float sk = dyk / dxk;
            float xi = (tv - xk) / dxk;
            xi = fminf(fmaxf(xi, 0.f), 1.f);
            const float om = 1.f - xi;
            const float num = dyk * (sk * xi * xi + dk * xi * om);
            const float den = sk + (dkp + dk - 2.f * sk) * xi * om;
            const float resin = yk + num / den;
            const float jn = sk * sk * (dkp * xi * xi + 2.f * sk * xi * om + dk * om * om);
            const float ljin = __logf(jn + 1e-10f) - __logf(den * den + 1e-10f);
            const float resout = scale * tv + (bottom - scale * left);
            const float ljout = __logf(scale + 1e-10f);
            out[(size_t)(row0 + lrow) * 64 + dc * 8 + dsl] = indom ? resin : resout;
            lja += indom ? ljin : ljout;
        }
        __syncthreads();
    }

    // log-det: reduce over the 8 dsl lanes of each row
    float lj = lja;
    lj += __shfl_xor(lj, 1, 64);
    lj += __shfl_xor(lj, 2, 64);
    lj += __shfl_xor(lj, 4, 64);
    if (dsl == 0) out[(size_t)32768 * 64 + row0 + lrow] = lj;
}

extern "C" void kernel_launch(void* const* d_in, const int* in_sizes, int n_in,
                              void* d_out, int out_size, void* d_ws, size_t ws_size,
                              hipStream_t stream) {
    const float* u1 = (const float*)d_in[0];
    const float* u2 = (const float*)d_in[1];
    const float* cd = (const float*)d_in[2];
    const float* W1 = (const float*)d_in[3];
    const float* b1 = (const float*)d_in[4];
    const float* W2 = (const float*)d_in[5];
    const float* b2 = (const float*)d_in[6];
    const float* W3 = (const float*)d_in[7];
    const float* b3 = (const float*)d_in[8];
    char* ws = (char*)d_ws;
    prep<<<136, 256, 0, stream>>>(W1, W2, W3, b3, ws);
    spline_main<<<512, 512, 0, stream>>>(u1, u2, cd, b1, b2, ws, (float*)d_out);
}